// Round 16
// baseline (415.925 us; speedup 1.0000x reference)
//
#include <hip/hip_runtime.h>

#define NN 50000
#define NE 800000
#define NG 256
#define NB ((NN + 255) / 256)   // scan blocks
#define N4 (NN * 128 / 4)       // float4 count of x (1.6M)

// ---------- bf16 helpers ----------
__device__ __forceinline__ unsigned short f2bf_rne(float f) {
    unsigned u = __float_as_uint(f);
    u += 0x7fffu + ((u >> 16) & 1u);   // round-to-nearest-even
    return (unsigned short)(u >> 16);
}
#define BF2F_LO(u) __uint_as_float((u) << 16)
#define BF2F_HI(u) __uint_as_float((u) & 0xffff0000u)

// ---------- merged: x->bf16 convert + degree histogram (deg pre-zeroed) ----------
__global__ void conv_hist(const float4* __restrict__ x, ushort4* __restrict__ xh,
                          const int* __restrict__ dst, int* __restrict__ deg,
                          int* __restrict__ eoff) {
    int i = blockIdx.x * 256 + threadIdx.x;
    if (i < N4) {
        float4 v = x[i];
        ushort4 o;
        o.x = f2bf_rne(v.x); o.y = f2bf_rne(v.y);
        o.z = f2bf_rne(v.z); o.w = f2bf_rne(v.w);
        xh[i] = o;
    }
    if (i < NE) eoff[i] = atomicAdd(&deg[dst[i]], 1);
}

// ---------- CSR scan ----------
__global__ void block_scan(const int* __restrict__ deg, int* __restrict__ iscan,
                           int* __restrict__ bsum) {
    __shared__ int sh[256];
    int t = threadIdx.x;
    int i = blockIdx.x * 256 + t;
    int v = (i < NN) ? deg[i] : 0;
    sh[t] = v;
    __syncthreads();
    #pragma unroll
    for (int off = 1; off < 256; off <<= 1) {
        int add = (t >= off) ? sh[t - off] : 0;
        __syncthreads();
        sh[t] += add;
        __syncthreads();
    }
    if (i < NN) iscan[i] = sh[t];
    if (t == 255) bsum[blockIdx.x] = sh[255];
}

__global__ void scan_bsum(const int* __restrict__ bsum, int* __restrict__ boff) {
    __shared__ int sh[256];
    int t = threadIdx.x;
    int v = (t < NB) ? bsum[t] : 0;
    sh[t] = v;
    __syncthreads();
    #pragma unroll
    for (int off = 1; off < 256; off <<= 1) {
        int add = (t >= off) ? sh[t - off] : 0;
        __syncthreads();
        sh[t] += add;
        __syncthreads();
    }
    if (t < NB) boff[t] = sh[t] - v;  // exclusive
}

// merged: rowptr finalize + graph-bounds (batch is sorted)
__global__ void finalize_bounds(const int* __restrict__ deg, const int* __restrict__ iscan,
                                const int* __restrict__ boff, int* __restrict__ rowptr,
                                const int* __restrict__ batch, int* __restrict__ gstart) {
    int i = blockIdx.x * 256 + threadIdx.x;
    if (i < NN) {
        rowptr[i] = iscan[i] - deg[i] + boff[blockIdx.x];
        int b = batch[i];
        if (i == 0) {
            for (int g = 0; g <= b; g++) gstart[g] = 0;
        } else {
            int p = batch[i - 1];
            for (int g = p + 1; g <= b; g++) gstart[g] = i;
        }
        if (i == NN - 1) {
            for (int g = b + 1; g <= NG; g++) gstart[g] = NN;
        }
    }
    if (i == 0) rowptr[NN] = NE;
}

__global__ void fill_csr2(const int* __restrict__ src, const int* __restrict__ dst,
                          const int* __restrict__ rowptr, const int* __restrict__ eoff,
                          int* __restrict__ esrc) {
    int e = blockIdx.x * blockDim.x + threadIdx.x;
    if (e >= NE) return;
    esrc[rowptr[dst[e]] + eoff[e]] = src[e];
}

// ---------- generic bf16 wave-cooperative gather (R11-proven) ----------
template <int C4>
__device__ __forceinline__ void gather_bf16(const uint4* __restrict__ x4,
                                            const int* __restrict__ esrc,
                                            int beg, int cnt, int node, int lane,
                                            float* a /* [8] */) {
    constexpr int EPI = 64 / C4;
    const int chunk = lane & (C4 - 1);
    const int esl   = lane / C4;
    #define ACC_U4(u) do { \
        a[0] += BF2F_LO((u).x); a[1] += BF2F_HI((u).x); \
        a[2] += BF2F_LO((u).y); a[3] += BF2F_HI((u).y); \
        a[4] += BF2F_LO((u).z); a[5] += BF2F_HI((u).z); \
        a[6] += BF2F_LO((u).w); a[7] += BF2F_HI((u).w); } while (0)
    if (esl == 0) { uint4 u = x4[(size_t)node * C4 + chunk]; ACC_U4(u); }
    for (int c = 0; c < cnt; c += 64) {
        int take = min(64, cnt - c);
        int myi = (lane < take) ? esrc[beg + c + lane] : 0;
        int i = 0;
        for (; i + 4 * EPI <= take; i += 4 * EPI) {
            int s0 = __shfl(myi, i + esl);
            int s1 = __shfl(myi, i + EPI + esl);
            int s2 = __shfl(myi, i + 2 * EPI + esl);
            int s3 = __shfl(myi, i + 3 * EPI + esl);
            uint4 u0 = x4[(size_t)s0 * C4 + chunk];
            uint4 u1 = x4[(size_t)s1 * C4 + chunk];
            uint4 u2 = x4[(size_t)s2 * C4 + chunk];
            uint4 u3 = x4[(size_t)s3 * C4 + chunk];
            ACC_U4(u0); ACC_U4(u1); ACC_U4(u2); ACC_U4(u3);
        }
        for (; i + EPI <= take; i += EPI) {
            int s = __shfl(myi, i + esl);
            uint4 u = x4[(size_t)s * C4 + chunk];
            ACC_U4(u);
        }
        int rem = take - i;
        if (rem > 0) {
            int s = __shfl(myi, i + ((esl < rem) ? esl : 0));
            uint4 u = x4[(size_t)s * C4 + chunk];
            if (esl < rem) ACC_U4(u);
        }
    }
    #undef ACC_U4
    for (int off = 32; off >= C4; off >>= 1) {
        #pragma unroll
        for (int q = 0; q < 8; q++)
            a[q] += __shfl_xor(a[q], off);
    }
}

// ---------- fused layer 0 (MT=64, 512 thr / 8 waves): bf16 gather x(128) -> MLP0+BN+relu -> xW1_1 -> z1h ----------
__global__ __launch_bounds__(512) void fused_L0(
        const unsigned short* __restrict__ xh, const int* __restrict__ esrc,
        const int* __restrict__ rowptr, unsigned short* __restrict__ z1h,
        const float* __restrict__ W1, const float* __restrict__ b1,
        const float* __restrict__ W2, const float* __restrict__ b2,
        const float* __restrict__ gamma, const float* __restrict__ beta,
        const float* __restrict__ mean, const float* __restrict__ var,
        const float* __restrict__ Wn /* W1_1: 128x64 */) {
    constexpr int MT = 64, LD = 132;
    __shared__ float sh[MT * LD];
    const int tid = threadIdx.x, wave = tid >> 6, lane = tid & 63;
    const int nodeBase = blockIdx.x * MT;

    // phase 1: gather (C4=16, EPI=4); 8 rows per wave
    for (int r = wave; r < MT; r += 8) {
        int node = nodeBase + r;
        float a[8] = {0, 0, 0, 0, 0, 0, 0, 0};
        if (node < NN) {
            int beg = rowptr[node], end = rowptr[node + 1];
            gather_bf16<16>((const uint4*)xh, esrc, beg, end - beg, node, lane, a);
        }
        if (lane < 16) {
            *(float4*)&sh[r * LD + lane * 8]     = make_float4(a[0], a[1], a[2], a[3]);
            *(float4*)&sh[r * LD + lane * 8 + 4] = make_float4(a[4], a[5], a[6], a[7]);
        }
    }
    __syncthreads();

    // GEMM1: 128->128, relu. CT=32, RT=16, RPT=4
    const int colid = tid % 32, rowid = tid / 32;
    const int c0 = colid * 4, r0 = rowid * 4;
    float acc[4][4];
    {
        float4 bv = *(const float4*)&b1[c0];
        #pragma unroll
        for (int i = 0; i < 4; i++) {
            acc[i][0] = bv.x; acc[i][1] = bv.y; acc[i][2] = bv.z; acc[i][3] = bv.w;
        }
        #pragma unroll 2
        for (int k4 = 0; k4 < 32; k4++) {
            float4 w[4];
            #pragma unroll
            for (int kk = 0; kk < 4; kk++)
                w[kk] = *(const float4*)&W1[(k4 * 4 + kk) * 128 + c0];
            #pragma unroll
            for (int i = 0; i < 4; i++) {
                float4 a = *(const float4*)&sh[(r0 + i) * LD + k4 * 4];
                const float av[4] = {a.x, a.y, a.z, a.w};
                #pragma unroll
                for (int kk = 0; kk < 4; kk++) {
                    const float* wp = (const float*)&w[kk];
                    #pragma unroll
                    for (int j = 0; j < 4; j++)
                        acc[i][j] = fmaf(av[kk], wp[j], acc[i][j]);
                }
            }
        }
    }
    __syncthreads();
    #pragma unroll
    for (int i = 0; i < 4; i++) {
        float4 h;
        h.x = fmaxf(acc[i][0], 0.f); h.y = fmaxf(acc[i][1], 0.f);
        h.z = fmaxf(acc[i][2], 0.f); h.w = fmaxf(acc[i][3], 0.f);
        *(float4*)&sh[(r0 + i) * LD + c0] = h;
    }
    __syncthreads();

    // GEMM2: 128->128, BN, relu
    {
        float4 bv = *(const float4*)&b2[c0];
        #pragma unroll
        for (int i = 0; i < 4; i++) {
            acc[i][0] = bv.x; acc[i][1] = bv.y; acc[i][2] = bv.z; acc[i][3] = bv.w;
        }
        #pragma unroll 2
        for (int k4 = 0; k4 < 32; k4++) {
            float4 w[4];
            #pragma unroll
            for (int kk = 0; kk < 4; kk++)
                w[kk] = *(const float4*)&W2[(k4 * 4 + kk) * 128 + c0];
            #pragma unroll
            for (int i = 0; i < 4; i++) {
                float4 a = *(const float4*)&sh[(r0 + i) * LD + k4 * 4];
                const float av[4] = {a.x, a.y, a.z, a.w};
                #pragma unroll
                for (int kk = 0; kk < 4; kk++) {
                    const float* wp = (const float*)&w[kk];
                    #pragma unroll
                    for (int j = 0; j < 4; j++)
                        acc[i][j] = fmaf(av[kk], wp[j], acc[i][j]);
                }
            }
        }
    }
    float4 gv = *(const float4*)&gamma[c0];
    float4 bev = *(const float4*)&beta[c0];
    float4 mv = *(const float4*)&mean[c0];
    float4 vv = *(const float4*)&var[c0];
    float scale[4], shift[4];
    {
        const float* gp = (const float*)&gv; const float* bp = (const float*)&bev;
        const float* mp = (const float*)&mv; const float* vp = (const float*)&vv;
        #pragma unroll
        for (int j = 0; j < 4; j++) {
            scale[j] = gp[j] * (1.0f / sqrtf(vp[j] + 1e-5f));
            shift[j] = bp[j] - mp[j] * scale[j];
        }
    }
    __syncthreads();
    #pragma unroll
    for (int i = 0; i < 4; i++) {
        float4 y;
        y.x = fmaxf(fmaf(acc[i][0], scale[0], shift[0]), 0.f);
        y.y = fmaxf(fmaf(acc[i][1], scale[1], shift[1]), 0.f);
        y.z = fmaxf(fmaf(acc[i][2], scale[2], shift[2]), 0.f);
        y.w = fmaxf(fmaf(acc[i][3], scale[3], shift[3]), 0.f);
        *(float4*)&sh[(r0 + i) * LD + c0] = y;
    }
    __syncthreads();

    // GEMM3: y(128) @ W1_1(128x64) -> z1 (bf16). CT=16, RT=32, RPT=2
    {
        const int colid2 = tid % 16, rowid2 = tid / 16;
        const int c0b = colid2 * 4, r0b = rowid2 * 2;
        float a3[2][4] = {};
        #pragma unroll 2
        for (int k4 = 0; k4 < 32; k4++) {
            float4 w[4];
            #pragma unroll
            for (int kk = 0; kk < 4; kk++)
                w[kk] = *(const float4*)&Wn[(k4 * 4 + kk) * 64 + c0b];
            #pragma unroll
            for (int i = 0; i < 2; i++) {
                float4 a = *(const float4*)&sh[(r0b + i) * LD + k4 * 4];
                const float av[4] = {a.x, a.y, a.z, a.w};
                #pragma unroll
                for (int kk = 0; kk < 4; kk++) {
                    const float* wp = (const float*)&w[kk];
                    #pragma unroll
                    for (int j = 0; j < 4; j++)
                        a3[i][j] = fmaf(av[kk], wp[j], a3[i][j]);
                }
            }
        }
        #pragma unroll
        for (int i = 0; i < 2; i++) {
            int node = nodeBase + r0b + i;
            if (node < NN) {
                ushort4 o;
                o.x = f2bf_rne(a3[i][0]); o.y = f2bf_rne(a3[i][1]);
                o.z = f2bf_rne(a3[i][2]); o.w = f2bf_rne(a3[i][3]);
                *(ushort4*)&z1h[(size_t)node * 64 + c0b] = o;
            }
        }
    }
}

// ---------- fused layer 1 (MT=64, 512 thr): bf16 gather z1(64) -> +b1,relu -> W2_1+BN+relu -> xW1_2 -> z2h ----------
__global__ __launch_bounds__(512) void fused_L1(
        const unsigned short* __restrict__ z1h, const int* __restrict__ esrc,
        const int* __restrict__ rowptr, unsigned short* __restrict__ z2h,
        const float* __restrict__ b1, const float* __restrict__ W2,
        const float* __restrict__ b2, const float* __restrict__ gamma,
        const float* __restrict__ beta, const float* __restrict__ mean,
        const float* __restrict__ var, const float* __restrict__ Wn /* W1_2: 64x32 */) {
    constexpr int MT = 64, LD = 68;
    __shared__ float sh[MT * LD];
    const int tid = threadIdx.x, wave = tid >> 6, lane = tid & 63;
    const int nodeBase = blockIdx.x * MT;

    // gather (C4=8, EPI=8) + bias + relu; 8 rows per wave
    for (int r = wave; r < MT; r += 8) {
        int node = nodeBase + r;
        float a[8] = {0, 0, 0, 0, 0, 0, 0, 0};
        if (node < NN) {
            int beg = rowptr[node], end = rowptr[node + 1];
            gather_bf16<8>((const uint4*)z1h, esrc, beg, end - beg, node, lane, a);
        }
        if (lane < 8) {
            float4 b0 = *(const float4*)&b1[lane * 8];
            float4 b4 = *(const float4*)&b1[lane * 8 + 4];
            *(float4*)&sh[r * LD + lane * 8] = make_float4(
                fmaxf(a[0] + b0.x, 0.f), fmaxf(a[1] + b0.y, 0.f),
                fmaxf(a[2] + b0.z, 0.f), fmaxf(a[3] + b0.w, 0.f));
            *(float4*)&sh[r * LD + lane * 8 + 4] = make_float4(
                fmaxf(a[4] + b4.x, 0.f), fmaxf(a[5] + b4.y, 0.f),
                fmaxf(a[6] + b4.z, 0.f), fmaxf(a[7] + b4.w, 0.f));
        }
    }
    __syncthreads();

    // GEMM_A: 64->64 (W2_1) + BN + relu. CT=16, RT=32, RPT=2
    const int colid = tid % 16, rowid = tid / 16;
    const int c0 = colid * 4, r0 = rowid * 2;
    float acc[2][4];
    {
        float4 bv = *(const float4*)&b2[c0];
        #pragma unroll
        for (int i = 0; i < 2; i++) {
            acc[i][0] = bv.x; acc[i][1] = bv.y; acc[i][2] = bv.z; acc[i][3] = bv.w;
        }
        #pragma unroll 2
        for (int k4 = 0; k4 < 16; k4++) {
            float4 w[4];
            #pragma unroll
            for (int kk = 0; kk < 4; kk++)
                w[kk] = *(const float4*)&W2[(k4 * 4 + kk) * 64 + c0];
            #pragma unroll
            for (int i = 0; i < 2; i++) {
                float4 a = *(const float4*)&sh[(r0 + i) * LD + k4 * 4];
                const float av[4] = {a.x, a.y, a.z, a.w};
                #pragma unroll
                for (int kk = 0; kk < 4; kk++) {
                    const float* wp = (const float*)&w[kk];
                    #pragma unroll
                    for (int j = 0; j < 4; j++)
                        acc[i][j] = fmaf(av[kk], wp[j], acc[i][j]);
                }
            }
        }
    }
    float4 gv = *(const float4*)&gamma[c0];
    float4 bev = *(const float4*)&beta[c0];
    float4 mv = *(const float4*)&mean[c0];
    float4 vv = *(const float4*)&var[c0];
    float scale[4], shift[4];
    {
        const float* gp = (const float*)&gv; const float* bp = (const float*)&bev;
        const float* mp = (const float*)&mv; const float* vp = (const float*)&vv;
        #pragma unroll
        for (int j = 0; j < 4; j++) {
            scale[j] = gp[j] * (1.0f / sqrtf(vp[j] + 1e-5f));
            shift[j] = bp[j] - mp[j] * scale[j];
        }
    }
    __syncthreads();
    #pragma unroll
    for (int i = 0; i < 2; i++) {
        float4 y;
        y.x = fmaxf(fmaf(acc[i][0], scale[0], shift[0]), 0.f);
        y.y = fmaxf(fmaf(acc[i][1], scale[1], shift[1]), 0.f);
        y.z = fmaxf(fmaf(acc[i][2], scale[2], shift[2]), 0.f);
        y.w = fmaxf(fmaf(acc[i][3], scale[3], shift[3]), 0.f);
        *(float4*)&sh[(r0 + i) * LD + c0] = y;
    }
    __syncthreads();

    // GEMM_B: y(64) @ W1_2(64x32) -> z2 (bf16). CT=8, RT=64, RPT=1
    {
        const int colid2 = tid % 8, rowid2 = tid / 8;
        const int c0b = colid2 * 4, r0b = rowid2;
        float a3[4] = {};
        #pragma unroll 2
        for (int k4 = 0; k4 < 16; k4++) {
            float4 w[4];
            #pragma unroll
            for (int kk = 0; kk < 4; kk++)
                w[kk] = *(const float4*)&Wn[(k4 * 4 + kk) * 32 + c0b];
            float4 a = *(const float4*)&sh[r0b * LD + k4 * 4];
            const float av[4] = {a.x, a.y, a.z, a.w};
            #pragma unroll
            for (int kk = 0; kk < 4; kk++) {
                const float* wp = (const float*)&w[kk];
                #pragma unroll
                for (int j = 0; j < 4; j++)
                    a3[j] = fmaf(av[kk], wp[j], a3[j]);
            }
        }
        int node = nodeBase + r0b;
        if (node < NN) {
            ushort4 o;
            o.x = f2bf_rne(a3[0]); o.y = f2bf_rne(a3[1]);
            o.z = f2bf_rne(a3[2]); o.w = f2bf_rne(a3[3]);
            *(ushort4*)&z2h[(size_t)node * 32 + c0b] = o;
        }
    }
}

// ---------- fused layer 2 (MT=64, 512 thr): bf16 gather z2(32) -> +b1,relu -> W2_2+BN -> xW_lin -> logits ----------
__global__ __launch_bounds__(512) void fused_L2(
        const unsigned short* __restrict__ z2h, const int* __restrict__ esrc,
        const int* __restrict__ rowptr, float* __restrict__ logits,
        const float* __restrict__ b1, const float* __restrict__ W2,
        const float* __restrict__ b2, const float* __restrict__ gamma,
        const float* __restrict__ beta, const float* __restrict__ mean,
        const float* __restrict__ var, const float* __restrict__ Wl,
        const float* __restrict__ bl) {
    constexpr int MT = 64, LD = 36;
    __shared__ float sh[MT * LD];
    const int tid = threadIdx.x, wave = tid >> 6, lane = tid & 63;
    const int nodeBase = blockIdx.x * MT;

    // gather (C4=4, EPI=16) + bias + relu; 8 rows per wave
    for (int r = wave; r < MT; r += 8) {
        int node = nodeBase + r;
        float a[8] = {0, 0, 0, 0, 0, 0, 0, 0};
        if (node < NN) {
            int beg = rowptr[node], end = rowptr[node + 1];
            gather_bf16<4>((const uint4*)z2h, esrc, beg, end - beg, node, lane, a);
        }
        if (lane < 4) {
            float4 b0 = *(const float4*)&b1[lane * 8];
            float4 b4 = *(const float4*)&b1[lane * 8 + 4];
            *(float4*)&sh[r * LD + lane * 8] = make_float4(
                fmaxf(a[0] + b0.x, 0.f), fmaxf(a[1] + b0.y, 0.f),
                fmaxf(a[2] + b0.z, 0.f), fmaxf(a[3] + b0.w, 0.f));
            *(float4*)&sh[r * LD + lane * 8 + 4] = make_float4(
                fmaxf(a[4] + b4.x, 0.f), fmaxf(a[5] + b4.y, 0.f),
                fmaxf(a[6] + b4.z, 0.f), fmaxf(a[7] + b4.w, 0.f));
        }
    }
    __syncthreads();

    // GEMM: 32->32 (W2_2) + BN (no relu), dot W_lin. CT=8, RT=64, RPT=1
    const int colid = tid % 8, rowid = tid / 8;
    const int c0 = colid * 4, r0 = rowid;
    float acc[4];
    {
        float4 bv = *(const float4*)&b2[c0];
        acc[0] = bv.x; acc[1] = bv.y; acc[2] = bv.z; acc[3] = bv.w;
        #pragma unroll
        for (int k4 = 0; k4 < 8; k4++) {
            float4 w[4];
            #pragma unroll
            for (int kk = 0; kk < 4; kk++)
                w[kk] = *(const float4*)&W2[(k4 * 4 + kk) * 32 + c0];
            float4 a = *(const float4*)&sh[r0 * LD + k4 * 4];
            const float av[4] = {a.x, a.y, a.z, a.w};
            #pragma unroll
            for (int kk = 0; kk < 4; kk++) {
                const float* wp = (const float*)&w[kk];
                #pragma unroll
                for (int j = 0; j < 4; j++)
                    acc[j] = fmaf(av[kk], wp[j], acc[j]);
            }
        }
    }
    float4 gv = *(const float4*)&gamma[c0];
    float4 bev = *(const float4*)&beta[c0];
    float4 mv = *(const float4*)&mean[c0];
    float4 vv = *(const float4*)&var[c0];
    float4 wl = *(const float4*)&Wl[c0];
    float p = 0.f;
    {
        const float* gp = (const float*)&gv; const float* bp = (const float*)&bev;
        const float* mp = (const float*)&mv; const float* vp = (const float*)&vv;
        const float* wp = (const float*)&wl;
        #pragma unroll
        for (int j = 0; j < 4; j++) {
            float sc = gp[j] * (1.0f / sqrtf(vp[j] + 1e-5f));
            float y = (acc[j] - mp[j]) * sc + bp[j];
            p = fmaf(y, wp[j], p);
        }
    }
    p += __shfl_xor(p, 1);
    p += __shfl_xor(p, 2);
    p += __shfl_xor(p, 4);
    int node = nodeBase + r0;
    if ((tid & 7) == 0 && node < NN)
        logits[node] = (p + bl[0]) * 0.2f;
}

// ---------- head ----------
__global__ __launch_bounds__(256) void seg_softmax(
        const float* __restrict__ logits, const int* __restrict__ gstart,
        float* __restrict__ out) {
    __shared__ float slog[1024];
    __shared__ float sred[4];
    __shared__ float sbc[2];
    int g = blockIdx.x;
    int beg = gstart[g], end = gstart[g + 1];
    int cnt = end - beg;
    int t = threadIdx.x;
    if (cnt <= 0) return;
    bool fits = (cnt <= 1024);

    float lmax = -3.402823466e+38f;
    for (int i = t; i < cnt; i += 256) {
        float lg = logits[beg + i];
        if (fits) slog[i] = lg;
        lmax = fmaxf(lmax, lg);
    }
    #pragma unroll
    for (int off = 32; off > 0; off >>= 1)
        lmax = fmaxf(lmax, __shfl_down(lmax, off));
    if ((t & 63) == 0) sred[t >> 6] = lmax;
    __syncthreads();
    if (t == 0) sbc[0] = fmaxf(fmaxf(sred[0], sred[1]), fmaxf(sred[2], sred[3]));
    __syncthreads();
    float gm = sbc[0];

    float lsum = 0.f;
    for (int i = t; i < cnt; i += 256) {
        float lg = fits ? slog[i] : logits[beg + i];
        float e = expf(lg - gm);
        if (fits) slog[i] = e;
        lsum += e;
    }
    #pragma unroll
    for (int off = 32; off > 0; off >>= 1)
        lsum += __shfl_down(lsum, off);
    __syncthreads();
    if ((t & 63) == 0) sred[t >> 6] = lsum;
    __syncthreads();
    if (t == 0) sbc[1] = (sred[0] + sred[1]) + (sred[2] + sred[3]);
    __syncthreads();
    float inv = 1.0f / sbc[1];

    for (int i = t; i < cnt; i += 256) {
        float e = fits ? slog[i] : expf(logits[beg + i] - gm);
        out[beg + i] = e * inv;
    }
}

// ---------- launch ----------
extern "C" void kernel_launch(void* const* d_in, const int* in_sizes, int n_in,
                              void* d_out, int out_size, void* d_ws, size_t ws_size,
                              hipStream_t stream) {
    const float* x    = (const float*)d_in[0];
    const int*   ei   = (const int*)d_in[1];
    const int*   srcI = ei;
    const int*   dstI = ei + NE;
    const int*   batch = (const int*)d_in[2];

    const float* P[29];
    for (int i = 0; i < 29; i++) P[i] = (const float*)d_in[i];
    const float* Wlin = P[27];
    const float* blin = P[28];

    unsigned short* xh  = (unsigned short*)d_ws;       // N x 128 bf16
    unsigned short* z1h = xh + (size_t)NN * 128;       // N x 64 bf16
    unsigned short* z2h = z1h + (size_t)NN * 64;       // N x 32 bf16
    float* logits = (float*)(z2h + (size_t)NN * 32);   // N
    int* gstart = (int*)(logits + NN);                 // NG+1
    int* deg    = gstart + NG + 1;                     // N
    int* iscan  = deg + NN;                            // N
    int* rowptr = iscan + NN;                          // N+1
    int* bsum   = rowptr + NN + 1;                     // NB
    int* boff   = bsum + NB;                           // NB
    int* eoff   = boff + NB;                           // E
    int* esrc   = eoff + NE;                           // E
    float* outp = (float*)d_out;

    const int TB = 256;

    // ---- merged convert + CSR histogram (grid covers N4 > NE) ----
    hipMemsetAsync(deg, 0, NN * sizeof(int), stream);
    conv_hist<<<(N4 + TB - 1) / TB, TB, 0, stream>>>(
        (const float4*)x, (ushort4*)xh, dstI, deg, eoff);

    block_scan<<<NB, 256, 0, stream>>>(deg, iscan, bsum);
    scan_bsum<<<1, 256, 0, stream>>>(bsum, boff);
    finalize_bounds<<<NB, 256, 0, stream>>>(deg, iscan, boff, rowptr, batch, gstart);
    fill_csr2<<<(NE + TB - 1) / TB, TB, 0, stream>>>(srcI, dstI, rowptr, eoff, esrc);

    const int FB64 = (NN + 63) / 64;

    fused_L0<<<FB64, 512, 0, stream>>>(xh, esrc, rowptr, z1h,
        P[3], P[4], P[5], P[6], P[7], P[8], P[9], P[10], P[11]);
    fused_L1<<<FB64, 512, 0, stream>>>(z1h, esrc, rowptr, z2h,
        P[12], P[13], P[14], P[15], P[16], P[17], P[18], P[19]);
    fused_L2<<<FB64, 512, 0, stream>>>(z2h, esrc, rowptr, logits,
        P[20], P[21], P[22], P[23], P[24], P[25], P[26], Wlin, blin);

    seg_softmax<<<NG, 256, 0, stream>>>(logits, gstart, outp);
}

// Round 17
// 368.874 us; speedup vs baseline: 1.1276x; 1.1276x over previous
//
#include <hip/hip_runtime.h>

#define NN 50000
#define NE 800000
#define NG 256
#define NB ((NN + 255) / 256)   // scan blocks
#define N4 (NN * 128 / 4)       // float4 count of x (1.6M)

// ---------- bf16 helpers ----------
__device__ __forceinline__ unsigned short f2bf_rne(float f) {
    unsigned u = __float_as_uint(f);
    u += 0x7fffu + ((u >> 16) & 1u);   // round-to-nearest-even
    return (unsigned short)(u >> 16);
}
#define BF2F_LO(u) __uint_as_float((u) << 16)
#define BF2F_HI(u) __uint_as_float((u) & 0xffff0000u)

// ---------- merged: x->bf16 convert + degree histogram (deg pre-zeroed) ----------
__global__ void conv_hist(const float4* __restrict__ x, ushort4* __restrict__ xh,
                          const int* __restrict__ dst, int* __restrict__ deg,
                          int* __restrict__ eoff) {
    int i = blockIdx.x * 256 + threadIdx.x;
    if (i < N4) {
        float4 v = x[i];
        ushort4 o;
        o.x = f2bf_rne(v.x); o.y = f2bf_rne(v.y);
        o.z = f2bf_rne(v.z); o.w = f2bf_rne(v.w);
        xh[i] = o;
    }
    if (i < NE) eoff[i] = atomicAdd(&deg[dst[i]], 1);
}

// ---------- CSR scan ----------
__global__ void block_scan(const int* __restrict__ deg, int* __restrict__ iscan,
                           int* __restrict__ bsum) {
    __shared__ int sh[256];
    int t = threadIdx.x;
    int i = blockIdx.x * 256 + t;
    int v = (i < NN) ? deg[i] : 0;
    sh[t] = v;
    __syncthreads();
    #pragma unroll
    for (int off = 1; off < 256; off <<= 1) {
        int add = (t >= off) ? sh[t - off] : 0;
        __syncthreads();
        sh[t] += add;
        __syncthreads();
    }
    if (i < NN) iscan[i] = sh[t];
    if (t == 255) bsum[blockIdx.x] = sh[255];
}

__global__ void scan_bsum(const int* __restrict__ bsum, int* __restrict__ boff) {
    __shared__ int sh[256];
    int t = threadIdx.x;
    int v = (t < NB) ? bsum[t] : 0;
    sh[t] = v;
    __syncthreads();
    #pragma unroll
    for (int off = 1; off < 256; off <<= 1) {
        int add = (t >= off) ? sh[t - off] : 0;
        __syncthreads();
        sh[t] += add;
        __syncthreads();
    }
    if (t < NB) boff[t] = sh[t] - v;  // exclusive
}

// merged: rowptr finalize + graph-bounds (batch is sorted)
__global__ void finalize_bounds(const int* __restrict__ deg, const int* __restrict__ iscan,
                                const int* __restrict__ boff, int* __restrict__ rowptr,
                                const int* __restrict__ batch, int* __restrict__ gstart) {
    int i = blockIdx.x * 256 + threadIdx.x;
    if (i < NN) {
        rowptr[i] = iscan[i] - deg[i] + boff[blockIdx.x];
        int b = batch[i];
        if (i == 0) {
            for (int g = 0; g <= b; g++) gstart[g] = 0;
        } else {
            int p = batch[i - 1];
            for (int g = p + 1; g <= b; g++) gstart[g] = i;
        }
        if (i == NN - 1) {
            for (int g = b + 1; g <= NG; g++) gstart[g] = NN;
        }
    }
    if (i == 0) rowptr[NN] = NE;
}

__global__ void fill_csr2(const int* __restrict__ src, const int* __restrict__ dst,
                          const int* __restrict__ rowptr, const int* __restrict__ eoff,
                          int* __restrict__ esrc) {
    int e = blockIdx.x * blockDim.x + threadIdx.x;
    if (e >= NE) return;
    esrc[rowptr[dst[e]] + eoff[e]] = src[e];
}

// ---------- generic bf16 wave-cooperative gather (R11-proven) ----------
template <int C4>
__device__ __forceinline__ void gather_bf16(const uint4* __restrict__ x4,
                                            const int* __restrict__ esrc,
                                            int beg, int cnt, int node, int lane,
                                            float* a /* [8] */) {
    constexpr int EPI = 64 / C4;
    const int chunk = lane & (C4 - 1);
    const int esl   = lane / C4;
    #define ACC_U4(u) do { \
        a[0] += BF2F_LO((u).x); a[1] += BF2F_HI((u).x); \
        a[2] += BF2F_LO((u).y); a[3] += BF2F_HI((u).y); \
        a[4] += BF2F_LO((u).z); a[5] += BF2F_HI((u).z); \
        a[6] += BF2F_LO((u).w); a[7] += BF2F_HI((u).w); } while (0)
    if (esl == 0) { uint4 u = x4[(size_t)node * C4 + chunk]; ACC_U4(u); }
    for (int c = 0; c < cnt; c += 64) {
        int take = min(64, cnt - c);
        int myi = (lane < take) ? esrc[beg + c + lane] : 0;
        int i = 0;
        for (; i + 4 * EPI <= take; i += 4 * EPI) {
            int s0 = __shfl(myi, i + esl);
            int s1 = __shfl(myi, i + EPI + esl);
            int s2 = __shfl(myi, i + 2 * EPI + esl);
            int s3 = __shfl(myi, i + 3 * EPI + esl);
            uint4 u0 = x4[(size_t)s0 * C4 + chunk];
            uint4 u1 = x4[(size_t)s1 * C4 + chunk];
            uint4 u2 = x4[(size_t)s2 * C4 + chunk];
            uint4 u3 = x4[(size_t)s3 * C4 + chunk];
            ACC_U4(u0); ACC_U4(u1); ACC_U4(u2); ACC_U4(u3);
        }
        for (; i + EPI <= take; i += EPI) {
            int s = __shfl(myi, i + esl);
            uint4 u = x4[(size_t)s * C4 + chunk];
            ACC_U4(u);
        }
        int rem = take - i;
        if (rem > 0) {
            int s = __shfl(myi, i + ((esl < rem) ? esl : 0));
            uint4 u = x4[(size_t)s * C4 + chunk];
            if (esl < rem) ACC_U4(u);
        }
    }
    #undef ACC_U4
    for (int off = 32; off >= C4; off >>= 1) {
        #pragma unroll
        for (int q = 0; q < 8; q++)
            a[q] += __shfl_xor(a[q], off);
    }
}

// ---------- standalone L0 gather: one wave per node (50000 waves, no LDS) ----------
__global__ __launch_bounds__(256) void gather_L0(
        const unsigned short* __restrict__ xh, const int* __restrict__ esrc,
        const int* __restrict__ rowptr, float* __restrict__ agg /* N x 128 fp32 */) {
    const int wave = threadIdx.x >> 6, lane = threadIdx.x & 63;
    const int node = blockIdx.x * 4 + wave;
    if (node >= NN) return;
    float a[8] = {0, 0, 0, 0, 0, 0, 0, 0};
    int beg = rowptr[node], end = rowptr[node + 1];
    gather_bf16<16>((const uint4*)xh, esrc, beg, end - beg, node, lane, a);
    if (lane < 16) {
        *(float4*)&agg[(size_t)node * 128 + lane * 8]     = make_float4(a[0], a[1], a[2], a[3]);
        *(float4*)&agg[(size_t)node * 128 + lane * 8 + 4] = make_float4(a[4], a[5], a[6], a[7]);
    }
}

// ---------- L0 GEMM (MT=64, 256 thr): coalesced agg load -> MLP0+BN+relu -> xW1_1 -> z1h ----------
__global__ __launch_bounds__(256) void gemm_L0(
        const float* __restrict__ agg, unsigned short* __restrict__ z1h,
        const float* __restrict__ W1, const float* __restrict__ b1,
        const float* __restrict__ W2, const float* __restrict__ b2,
        const float* __restrict__ gamma, const float* __restrict__ beta,
        const float* __restrict__ mean, const float* __restrict__ var,
        const float* __restrict__ Wn /* W1_1: 128x64 */) {
    constexpr int MT = 64, LD = 132;
    __shared__ float sh[MT * LD];
    const int tid = threadIdx.x;
    const int nodeBase = blockIdx.x * MT;

    // stage agg tile, coalesced float4
    for (int idx = tid; idx < MT * 32; idx += 256) {
        int row = idx >> 5, c4 = idx & 31;
        int node = nodeBase + row;
        float4 v = (node < NN) ? ((const float4*)agg)[(size_t)node * 32 + c4]
                               : make_float4(0.f, 0.f, 0.f, 0.f);
        *(float4*)&sh[row * LD + c4 * 4] = v;
    }
    __syncthreads();

    // GEMM1: 128->128, relu. CT=32, RT=8, RPT=8
    const int colid = tid % 32, rowid = tid / 32;
    const int c0 = colid * 4, r0 = rowid * 8;
    float acc[8][4];
    {
        float4 bv = *(const float4*)&b1[c0];
        #pragma unroll
        for (int i = 0; i < 8; i++) {
            acc[i][0] = bv.x; acc[i][1] = bv.y; acc[i][2] = bv.z; acc[i][3] = bv.w;
        }
        #pragma unroll 2
        for (int k4 = 0; k4 < 32; k4++) {
            float4 w[4];
            #pragma unroll
            for (int kk = 0; kk < 4; kk++)
                w[kk] = *(const float4*)&W1[(k4 * 4 + kk) * 128 + c0];
            #pragma unroll
            for (int i = 0; i < 8; i++) {
                float4 a = *(const float4*)&sh[(r0 + i) * LD + k4 * 4];
                const float av[4] = {a.x, a.y, a.z, a.w};
                #pragma unroll
                for (int kk = 0; kk < 4; kk++) {
                    const float* wp = (const float*)&w[kk];
                    #pragma unroll
                    for (int j = 0; j < 4; j++)
                        acc[i][j] = fmaf(av[kk], wp[j], acc[i][j]);
                }
            }
        }
    }
    __syncthreads();
    #pragma unroll
    for (int i = 0; i < 8; i++) {
        float4 h;
        h.x = fmaxf(acc[i][0], 0.f); h.y = fmaxf(acc[i][1], 0.f);
        h.z = fmaxf(acc[i][2], 0.f); h.w = fmaxf(acc[i][3], 0.f);
        *(float4*)&sh[(r0 + i) * LD + c0] = h;
    }
    __syncthreads();

    // GEMM2: 128->128, BN, relu
    {
        float4 bv = *(const float4*)&b2[c0];
        #pragma unroll
        for (int i = 0; i < 8; i++) {
            acc[i][0] = bv.x; acc[i][1] = bv.y; acc[i][2] = bv.z; acc[i][3] = bv.w;
        }
        #pragma unroll 2
        for (int k4 = 0; k4 < 32; k4++) {
            float4 w[4];
            #pragma unroll
            for (int kk = 0; kk < 4; kk++)
                w[kk] = *(const float4*)&W2[(k4 * 4 + kk) * 128 + c0];
            #pragma unroll
            for (int i = 0; i < 8; i++) {
                float4 a = *(const float4*)&sh[(r0 + i) * LD + k4 * 4];
                const float av[4] = {a.x, a.y, a.z, a.w};
                #pragma unroll
                for (int kk = 0; kk < 4; kk++) {
                    const float* wp = (const float*)&w[kk];
                    #pragma unroll
                    for (int j = 0; j < 4; j++)
                        acc[i][j] = fmaf(av[kk], wp[j], acc[i][j]);
                }
            }
        }
    }
    float4 gv = *(const float4*)&gamma[c0];
    float4 bev = *(const float4*)&beta[c0];
    float4 mv = *(const float4*)&mean[c0];
    float4 vv = *(const float4*)&var[c0];
    float scale[4], shift[4];
    {
        const float* gp = (const float*)&gv; const float* bp = (const float*)&bev;
        const float* mp = (const float*)&mv; const float* vp = (const float*)&vv;
        #pragma unroll
        for (int j = 0; j < 4; j++) {
            scale[j] = gp[j] * (1.0f / sqrtf(vp[j] + 1e-5f));
            shift[j] = bp[j] - mp[j] * scale[j];
        }
    }
    __syncthreads();
    #pragma unroll
    for (int i = 0; i < 8; i++) {
        float4 y;
        y.x = fmaxf(fmaf(acc[i][0], scale[0], shift[0]), 0.f);
        y.y = fmaxf(fmaf(acc[i][1], scale[1], shift[1]), 0.f);
        y.z = fmaxf(fmaf(acc[i][2], scale[2], shift[2]), 0.f);
        y.w = fmaxf(fmaf(acc[i][3], scale[3], shift[3]), 0.f);
        *(float4*)&sh[(r0 + i) * LD + c0] = y;
    }
    __syncthreads();

    // GEMM3: y(128) @ W1_1(128x64) -> z1 (bf16). CT=16, RT=16, RPT=4
    {
        const int colid2 = tid % 16, rowid2 = tid / 16;
        const int c0b = colid2 * 4, r0b = rowid2 * 4;
        float a3[4][4] = {};
        #pragma unroll 2
        for (int k4 = 0; k4 < 32; k4++) {
            float4 w[4];
            #pragma unroll
            for (int kk = 0; kk < 4; kk++)
                w[kk] = *(const float4*)&Wn[(k4 * 4 + kk) * 64 + c0b];
            #pragma unroll
            for (int i = 0; i < 4; i++) {
                float4 a = *(const float4*)&sh[(r0b + i) * LD + k4 * 4];
                const float av[4] = {a.x, a.y, a.z, a.w};
                #pragma unroll
                for (int kk = 0; kk < 4; kk++) {
                    const float* wp = (const float*)&w[kk];
                    #pragma unroll
                    for (int j = 0; j < 4; j++)
                        a3[i][j] = fmaf(av[kk], wp[j], a3[i][j]);
                }
            }
        }
        #pragma unroll
        for (int i = 0; i < 4; i++) {
            int node = nodeBase + r0b + i;
            if (node < NN) {
                ushort4 o;
                o.x = f2bf_rne(a3[i][0]); o.y = f2bf_rne(a3[i][1]);
                o.z = f2bf_rne(a3[i][2]); o.w = f2bf_rne(a3[i][3]);
                *(ushort4*)&z1h[(size_t)node * 64 + c0b] = o;
            }
        }
    }
}

// ---------- fused layer 1 (MT=32, R11-proven): bf16 gather z1(64) -> +b1,relu -> W2_1+BN+relu -> xW1_2 -> z2h ----------
__global__ __launch_bounds__(256) void fused_L1(
        const unsigned short* __restrict__ z1h, const int* __restrict__ esrc,
        const int* __restrict__ rowptr, unsigned short* __restrict__ z2h,
        const float* __restrict__ b1, const float* __restrict__ W2,
        const float* __restrict__ b2, const float* __restrict__ gamma,
        const float* __restrict__ beta, const float* __restrict__ mean,
        const float* __restrict__ var, const float* __restrict__ Wn /* W1_2: 64x32 */) {
    constexpr int MT = 32, LD = 68;
    __shared__ float sh[MT * LD];
    const int tid = threadIdx.x, wave = tid >> 6, lane = tid & 63;
    const int nodeBase = blockIdx.x * MT;

    for (int r = wave; r < MT; r += 4) {
        int node = nodeBase + r;
        float a[8] = {0, 0, 0, 0, 0, 0, 0, 0};
        if (node < NN) {
            int beg = rowptr[node], end = rowptr[node + 1];
            gather_bf16<8>((const uint4*)z1h, esrc, beg, end - beg, node, lane, a);
        }
        if (lane < 8) {
            float4 b0 = *(const float4*)&b1[lane * 8];
            float4 b4 = *(const float4*)&b1[lane * 8 + 4];
            *(float4*)&sh[r * LD + lane * 8] = make_float4(
                fmaxf(a[0] + b0.x, 0.f), fmaxf(a[1] + b0.y, 0.f),
                fmaxf(a[2] + b0.z, 0.f), fmaxf(a[3] + b0.w, 0.f));
            *(float4*)&sh[r * LD + lane * 8 + 4] = make_float4(
                fmaxf(a[4] + b4.x, 0.f), fmaxf(a[5] + b4.y, 0.f),
                fmaxf(a[6] + b4.z, 0.f), fmaxf(a[7] + b4.w, 0.f));
        }
    }
    __syncthreads();

    // GEMM_A: 64->64 (W2_1) + BN + relu. CT=16, RT=16, RPT=2
    const int colid = tid % 16, rowid = tid / 16;
    const int c0 = colid * 4, r0 = rowid * 2;
    float acc[2][4];
    {
        float4 bv = *(const float4*)&b2[c0];
        #pragma unroll
        for (int i = 0; i < 2; i++) {
            acc[i][0] = bv.x; acc[i][1] = bv.y; acc[i][2] = bv.z; acc[i][3] = bv.w;
        }
        #pragma unroll 2
        for (int k4 = 0; k4 < 16; k4++) {
            float4 w[4];
            #pragma unroll
            for (int kk = 0; kk < 4; kk++)
                w[kk] = *(const float4*)&W2[(k4 * 4 + kk) * 64 + c0];
            #pragma unroll
            for (int i = 0; i < 2; i++) {
                float4 a = *(const float4*)&sh[(r0 + i) * LD + k4 * 4];
                const float av[4] = {a.x, a.y, a.z, a.w};
                #pragma unroll
                for (int kk = 0; kk < 4; kk++) {
                    const float* wp = (const float*)&w[kk];
                    #pragma unroll
                    for (int j = 0; j < 4; j++)
                        acc[i][j] = fmaf(av[kk], wp[j], acc[i][j]);
                }
            }
        }
    }
    float4 gv = *(const float4*)&gamma[c0];
    float4 bev = *(const float4*)&beta[c0];
    float4 mv = *(const float4*)&mean[c0];
    float4 vv = *(const float4*)&var[c0];
    float scale[4], shift[4];
    {
        const float* gp = (const float*)&gv; const float* bp = (const float*)&bev;
        const float* mp = (const float*)&mv; const float* vp = (const float*)&vv;
        #pragma unroll
        for (int j = 0; j < 4; j++) {
            scale[j] = gp[j] * (1.0f / sqrtf(vp[j] + 1e-5f));
            shift[j] = bp[j] - mp[j] * scale[j];
        }
    }
    __syncthreads();
    #pragma unroll
    for (int i = 0; i < 2; i++) {
        float4 y;
        y.x = fmaxf(fmaf(acc[i][0], scale[0], shift[0]), 0.f);
        y.y = fmaxf(fmaf(acc[i][1], scale[1], shift[1]), 0.f);
        y.z = fmaxf(fmaf(acc[i][2], scale[2], shift[2]), 0.f);
        y.w = fmaxf(fmaf(acc[i][3], scale[3], shift[3]), 0.f);
        *(float4*)&sh[(r0 + i) * LD + c0] = y;
    }
    __syncthreads();

    // GEMM_B: y(64) @ W1_2(64x32) -> z2 (bf16). CT=8, RT=32, RPT=1
    {
        const int colid2 = tid % 8, rowid2 = tid / 8;
        const int c0b = colid2 * 4, r0b = rowid2;
        float a3[4] = {};
        #pragma unroll 2
        for (int k4 = 0; k4 < 16; k4++) {
            float4 w[4];
            #pragma unroll
            for (int kk = 0; kk < 4; kk++)
                w[kk] = *(const float4*)&Wn[(k4 * 4 + kk) * 32 + c0b];
            float4 a = *(const float4*)&sh[r0b * LD + k4 * 4];
            const float av[4] = {a.x, a.y, a.z, a.w};
            #pragma unroll
            for (int kk = 0; kk < 4; kk++) {
                const float* wp = (const float*)&w[kk];
                #pragma unroll
                for (int j = 0; j < 4; j++)
                    a3[j] = fmaf(av[kk], wp[j], a3[j]);
            }
        }
        int node = nodeBase + r0b;
        if (node < NN) {
            ushort4 o;
            o.x = f2bf_rne(a3[0]); o.y = f2bf_rne(a3[1]);
            o.z = f2bf_rne(a3[2]); o.w = f2bf_rne(a3[3]);
            *(ushort4*)&z2h[(size_t)node * 32 + c0b] = o;
        }
    }
}

// ---------- fused layer 2 (MT=32, R11-proven): bf16 gather z2(32) -> +b1,relu -> W2_2+BN -> xW_lin -> logits ----------
__global__ __launch_bounds__(256) void fused_L2(
        const unsigned short* __restrict__ z2h, const int* __restrict__ esrc,
        const int* __restrict__ rowptr, float* __restrict__ logits,
        const float* __restrict__ b1, const float* __restrict__ W2,
        const float* __restrict__ b2, const float* __restrict__ gamma,
        const float* __restrict__ beta, const float* __restrict__ mean,
        const float* __restrict__ var, const float* __restrict__ Wl,
        const float* __restrict__ bl) {
    constexpr int MT = 32, LD = 36;
    __shared__ float sh[MT * LD];
    const int tid = threadIdx.x, wave = tid >> 6, lane = tid & 63;
    const int nodeBase = blockIdx.x * MT;

    for (int r = wave; r < MT; r += 4) {
        int node = nodeBase + r;
        float a[8] = {0, 0, 0, 0, 0, 0, 0, 0};
        if (node < NN) {
            int beg = rowptr[node], end = rowptr[node + 1];
            gather_bf16<4>((const uint4*)z2h, esrc, beg, end - beg, node, lane, a);
        }
        if (lane < 4) {
            float4 b0 = *(const float4*)&b1[lane * 8];
            float4 b4 = *(const float4*)&b1[lane * 8 + 4];
            *(float4*)&sh[r * LD + lane * 8] = make_float4(
                fmaxf(a[0] + b0.x, 0.f), fmaxf(a[1] + b0.y, 0.f),
                fmaxf(a[2] + b0.z, 0.f), fmaxf(a[3] + b0.w, 0.f));
            *(float4*)&sh[r * LD + lane * 8 + 4] = make_float4(
                fmaxf(a[4] + b4.x, 0.f), fmaxf(a[5] + b4.y, 0.f),
                fmaxf(a[6] + b4.z, 0.f), fmaxf(a[7] + b4.w, 0.f));
        }
    }
    __syncthreads();

    // GEMM: 32->32 (W2_2) + BN (no relu), dot W_lin. CT=8, RT=32, RPT=1
    const int colid = tid % 8, rowid = tid / 8;
    const int c0 = colid * 4, r0 = rowid;
    float acc[4];
    {
        float4 bv = *(const float4*)&b2[c0];
        acc[0] = bv.x; acc[1] = bv.y; acc[2] = bv.z; acc[3] = bv.w;
        #pragma unroll
        for (int k4 = 0; k4 < 8; k4++) {
            float4 w[4];
            #pragma unroll
            for (int kk = 0; kk < 4; kk++)
                w[kk] = *(const float4*)&W2[(k4 * 4 + kk) * 32 + c0];
            float4 a = *(const float4*)&sh[r0 * LD + k4 * 4];
            const float av[4] = {a.x, a.y, a.z, a.w};
            #pragma unroll
            for (int kk = 0; kk < 4; kk++) {
                const float* wp = (const float*)&w[kk];
                #pragma unroll
                for (int j = 0; j < 4; j++)
                    acc[j] = fmaf(av[kk], wp[j], acc[j]);
            }
        }
    }
    float4 gv = *(const float4*)&gamma[c0];
    float4 bev = *(const float4*)&beta[c0];
    float4 mv = *(const float4*)&mean[c0];
    float4 vv = *(const float4*)&var[c0];
    float4 wl = *(const float4*)&Wl[c0];
    float p = 0.f;
    {
        const float* gp = (const float*)&gv; const float* bp = (const float*)&bev;
        const float* mp = (const float*)&mv; const float* vp = (const float*)&vv;
        const float* wp = (const float*)&wl;
        #pragma unroll
        for (int j = 0; j < 4; j++) {
            float sc = gp[j] * (1.0f / sqrtf(vp[j] + 1e-5f));
            float y = (acc[j] - mp[j]) * sc + bp[j];
            p = fmaf(y, wp[j], p);
        }
    }
    p += __shfl_xor(p, 1);
    p += __shfl_xor(p, 2);
    p += __shfl_xor(p, 4);
    int node = nodeBase + r0;
    if ((tid & 7) == 0 && node < NN)
        logits[node] = (p + bl[0]) * 0.2f;
}

// ---------- head ----------
__global__ __launch_bounds__(256) void seg_softmax(
        const float* __restrict__ logits, const int* __restrict__ gstart,
        float* __restrict__ out) {
    __shared__ float slog[1024];
    __shared__ float sred[4];
    __shared__ float sbc[2];
    int g = blockIdx.x;
    int beg = gstart[g], end = gstart[g + 1];
    int cnt = end - beg;
    int t = threadIdx.x;
    if (cnt <= 0) return;
    bool fits = (cnt <= 1024);

    float lmax = -3.402823466e+38f;
    for (int i = t; i < cnt; i += 256) {
        float lg = logits[beg + i];
        if (fits) slog[i] = lg;
        lmax = fmaxf(lmax, lg);
    }
    #pragma unroll
    for (int off = 32; off > 0; off >>= 1)
        lmax = fmaxf(lmax, __shfl_down(lmax, off));
    if ((t & 63) == 0) sred[t >> 6] = lmax;
    __syncthreads();
    if (t == 0) sbc[0] = fmaxf(fmaxf(sred[0], sred[1]), fmaxf(sred[2], sred[3]));
    __syncthreads();
    float gm = sbc[0];

    float lsum = 0.f;
    for (int i = t; i < cnt; i += 256) {
        float lg = fits ? slog[i] : logits[beg + i];
        float e = expf(lg - gm);
        if (fits) slog[i] = e;
        lsum += e;
    }
    #pragma unroll
    for (int off = 32; off > 0; off >>= 1)
        lsum += __shfl_down(lsum, off);
    __syncthreads();
    if ((t & 63) == 0) sred[t >> 6] = lsum;
    __syncthreads();
    if (t == 0) sbc[1] = (sred[0] + sred[1]) + (sred[2] + sred[3]);
    __syncthreads();
    float inv = 1.0f / sbc[1];

    for (int i = t; i < cnt; i += 256) {
        float e = fits ? slog[i] : expf(logits[beg + i] - gm);
        out[beg + i] = e * inv;
    }
}

// ---------- launch ----------
extern "C" void kernel_launch(void* const* d_in, const int* in_sizes, int n_in,
                              void* d_out, int out_size, void* d_ws, size_t ws_size,
                              hipStream_t stream) {
    const float* x    = (const float*)d_in[0];
    const int*   ei   = (const int*)d_in[1];
    const int*   srcI = ei;
    const int*   dstI = ei + NE;
    const int*   batch = (const int*)d_in[2];

    const float* P[29];
    for (int i = 0; i < 29; i++) P[i] = (const float*)d_in[i];
    const float* Wlin = P[27];
    const float* blin = P[28];

    unsigned short* xh  = (unsigned short*)d_ws;       // N x 128 bf16
    unsigned short* z1h = xh + (size_t)NN * 128;       // N x 64 bf16
    unsigned short* z2h = z1h + (size_t)NN * 64;       // N x 32 bf16
    float* logits = (float*)(z2h + (size_t)NN * 32);   // N
    int* gstart = (int*)(logits + NN);                 // NG+1
    int* deg    = gstart + NG + 1;                     // N
    int* iscan  = deg + NN;                            // N
    int* rowptr = iscan + NN;                          // N+1
    int* bsum   = rowptr + NN + 1;                     // NB
    int* boff   = bsum + NB;                           // NB
    int* eoff   = boff + NB;                           // E
    int* esrc   = eoff + NE;                           // E
    float* agg  = (float*)(esrc + NE);                 // N x 128 fp32
    float* outp = (float*)d_out;

    const int TB = 256;

    // ---- merged convert + CSR histogram (grid covers N4 > NE) ----
    hipMemsetAsync(deg, 0, NN * sizeof(int), stream);
    conv_hist<<<(N4 + TB - 1) / TB, TB, 0, stream>>>(
        (const float4*)x, (ushort4*)xh, dstI, deg, eoff);

    block_scan<<<NB, 256, 0, stream>>>(deg, iscan, bsum);
    scan_bsum<<<1, 256, 0, stream>>>(bsum, boff);
    finalize_bounds<<<NB, 256, 0, stream>>>(deg, iscan, boff, rowptr, batch, gstart);
    fill_csr2<<<(NE + TB - 1) / TB, TB, 0, stream>>>(srcI, dstI, rowptr, eoff, esrc);

    const int GB  = (NN + 3) / 4;      // gather_L0: 1 wave/node
    const int FB64 = (NN + 63) / 64;
    const int FB32 = (NN + 31) / 32;

    gather_L0<<<GB, 256, 0, stream>>>(xh, esrc, rowptr, agg);
    gemm_L0<<<FB64, 256, 0, stream>>>(agg, z1h,
        P[3], P[4], P[5], P[6], P[7], P[8], P[9], P[10], P[11]);
    fused_L1<<<FB32, 256, 0, stream>>>(z1h, esrc, rowptr, z2h,
        P[12], P[13], P[14], P[15], P[16], P[17], P[18], P[19]);
    fused_L2<<<FB32, 256, 0, stream>>>(z2h, esrc, rowptr, logits,
        P[20], P[21], P[22], P[23], P[24], P[25], P[26], Wlin, blin);

    seg_softmax<<<NG, 256, 0, stream>>>(logits, gstart, outp);
}